// Round 7
// baseline (1471.588 us; speedup 1.0000x reference)
//
#include <hip/hip_runtime.h>

// MyTransformer: 6-enc + 6-dec, S=1024, D=512, H=8x64, FF=2048.
// Round 6: weight-GEMMs read fp32 weights directly (reg-staged B with RNE cvt,
// issue-early/write-late); no weight pre-conversion pass. Tile 128x64 per block
// (wave = 32x64, 16 MFMA : 12 ds_read per K-step), A via global_load_lds depth-3,
// B LDS depth-2. Fused flash attention; split-K slabs + LN-merge (templated).

#define NLAY 6

typedef __attribute__((ext_vector_type(8))) short short8;
typedef __attribute__((ext_vector_type(4))) short short4v;
typedef __attribute__((ext_vector_type(4))) float f32x4;

typedef __attribute__((address_space(3))) short lds_short;
typedef __attribute__((address_space(1))) const unsigned short g_ushort;

__device__ __forceinline__ void gload16(const unsigned short* g, short* l) {
    __builtin_amdgcn_global_load_lds((g_ushort*)g, (lds_short*)l, 16, 0, 0);
}

__device__ __forceinline__ void waitvm(int n) {   // wave-uniform literal waits
    if (n == 0)      asm volatile("s_waitcnt vmcnt(0)" ::: "memory");
    else if (n == 4) asm volatile("s_waitcnt vmcnt(4)" ::: "memory");
    else if (n == 8) asm volatile("s_waitcnt vmcnt(8)" ::: "memory");
    else             asm volatile("s_waitcnt vmcnt(12)" ::: "memory");
}

__device__ __forceinline__ void waitlgkm0() {
    asm volatile("s_waitcnt lgkmcnt(0)" ::: "memory");
}

__device__ inline unsigned short f2bu(float x) {
    unsigned u = __builtin_bit_cast(unsigned, x);
    unsigned r = (u + 0x7fffu + ((u >> 16) & 1u)) >> 16;   // RNE
    return (unsigned short)r;
}

// ------ weight GEMM: C = A(bf16) @ B(fp32->bf16)^T + bias, tile 128x64 -------
// A: [M][K] bf16 (lda); B: [N][K] fp32 (ldb), converted during staging.
// 256 thr = 4 waves; wave w owns rows [w*32, w*32+32) x all 64 cols.
// A: 3-buffer LDS via global_load_lds; B: regs (2 sets) -> swizzled LDS (2 buf).
// Steady-state wait vmcnt(8). Split-K: element offset z*kz, slab C += z*sC.
// If A2: blocks with n0 >= a2_col read A2. If VTp: cols >= vt_col0 scatter VT.
template<bool RELU, bool OBF16>
__global__ __launch_bounds__(256)
void gemmW_k(const unsigned short* __restrict__ A,
             const unsigned short* __restrict__ A2, int a2_col, int lda,
             const float* __restrict__ B, int ldb,
             const float* __restrict__ bias,
             void* __restrict__ Cv, int ldc, long sC,
             int K, unsigned short* __restrict__ VTp, int vt_col0, int kz)
{
    __shared__ __align__(16) short As[3][128 * 64];   // 48 KB
    __shared__ __align__(16) short Bs[2][64 * 64];    // 16 KB
    const int bz = blockIdx.z;
    const int m0 = blockIdx.y * 128;
    const int n0 = blockIdx.x * 64;
    if (A2 && n0 >= a2_col) A = A2;
    A += (long)bz * kz;
    B += (long)bz * kz;
    const int tid = threadIdx.x;
    const int w  = tid >> 6;
    const int l  = tid & 63;
    const int fr = l & 15;
    const int kc = l >> 4;

    // B staging coords: thread -> (row, 16-float chunk)
    const int brow = tid >> 2;              // 0..63  (B row = output col)
    const int bk16 = (tid & 3) * 16;        // k offset of this thread's chunk
    const int bs0  = (((tid & 3) * 2)     ^ (brow & 7)) * 8;
    const int bs1  = (((tid & 3) * 2 + 1) ^ (brow & 7)) * 8;

    f32x4 acc[2][4] = {};
    const int T = K >> 6;

    auto FILL_A = [&](int t) {
        const int buf = t % 3;
        const int k0 = t * 64;
        #pragma unroll
        for (int it = 0; it < 4; ++it) {
            const int row = w * 32 + it * 8 + (l >> 3);
            const int sl  = ((l & 7) ^ (row & 7)) * 8;
            gload16(A + (long)(m0 + row) * lda + k0 + sl, &As[buf][(w * 32 + it * 8) * 64]);
        }
    };
    auto ISSUE_B = [&](int t, float4 (&br)[4]) {
        const float* src = B + (long)(n0 + brow) * ldb + t * 64 + bk16;
        #pragma unroll
        for (int i = 0; i < 4; ++i) br[i] = *(const float4*)(src + i * 4);
    };
    auto WRITE_B = [&](int t, const float4 (&br)[4]) {
        const int buf = t & 1;
        short8 v0, v1;
        v0[0] = (short)f2bu(br[0].x); v0[1] = (short)f2bu(br[0].y);
        v0[2] = (short)f2bu(br[0].z); v0[3] = (short)f2bu(br[0].w);
        v0[4] = (short)f2bu(br[1].x); v0[5] = (short)f2bu(br[1].y);
        v0[6] = (short)f2bu(br[1].z); v0[7] = (short)f2bu(br[1].w);
        v1[0] = (short)f2bu(br[2].x); v1[1] = (short)f2bu(br[2].y);
        v1[2] = (short)f2bu(br[2].z); v1[3] = (short)f2bu(br[2].w);
        v1[4] = (short)f2bu(br[3].x); v1[5] = (short)f2bu(br[3].y);
        v1[6] = (short)f2bu(br[3].z); v1[7] = (short)f2bu(br[3].w);
        *(short8*)&Bs[buf][brow * 64 + bs0] = v0;
        *(short8*)&Bs[buf][brow * 64 + bs1] = v1;
    };
    auto COMPUTE = [&](int t) {
        const int ab = t % 3, bb = t & 1;
        #pragma unroll
        for (int ks = 0; ks < 2; ++ks) {
            const int sl = ((ks * 4 + kc) ^ (fr & 7)) * 8;
            short8 af[2], bf[4];
            #pragma unroll
            for (int r = 0; r < 2; ++r)
                af[r] = *(const short8*)&As[ab][(w * 32 + r * 16 + fr) * 64 + sl];
            #pragma unroll
            for (int c = 0; c < 4; ++c)
                bf[c] = *(const short8*)&Bs[bb][(c * 16 + fr) * 64 + sl];
            #pragma unroll
            for (int r = 0; r < 2; ++r)
                #pragma unroll
                for (int c = 0; c < 4; ++c)
                    acc[r][c] = __builtin_amdgcn_mfma_f32_16x16x32_bf16(af[r], bf[c], acc[r][c], 0, 0, 0);
        }
    };

    float4 br0[4], br1[4];

    // prologue: A0,B0,A1,B1 in flight -> wait oldest 8 -> write B0 -> barrier
    FILL_A(0); ISSUE_B(0, br0);
    FILL_A(1); ISSUE_B(1, br1);
    waitvm(8);
    __builtin_amdgcn_sched_barrier(0);
    WRITE_B(0, br0);
    waitlgkm0();
    __builtin_amdgcn_s_barrier();

    for (int t = 0; t < T; ++t) {
        if (t + 2 < T) {
            FILL_A(t + 2);
            if (t & 1) ISSUE_B(t + 2, br1); else ISSUE_B(t + 2, br0);
        }
        COMPUTE(t);
        waitvm((t + 2 < T) ? 8 : 0);
        __builtin_amdgcn_sched_barrier(0);
        if (t + 1 < T) {
            if (t & 1) WRITE_B(t + 1, br0); else WRITE_B(t + 1, br1);
        }
        waitlgkm0();
        __builtin_amdgcn_s_barrier();
    }

    #pragma unroll
    for (int c = 0; c < 4; ++c) {
        const int n = n0 + c * 16 + fr;
        const float bv = bias ? bias[n] : 0.0f;
        const bool do_vt = (VTp != nullptr) && (n >= vt_col0);
        #pragma unroll
        for (int r = 0; r < 2; ++r) {
            #pragma unroll
            for (int i = 0; i < 4; ++i) {
                const long m = m0 + w * 32 + r * 16 + kc * 4 + i;
                float v = acc[r][c][i] + bv;
                if (RELU) v = fmaxf(v, 0.0f);
                if (OBF16) ((unsigned short*)Cv)[bz * sC + m * ldc + n] = f2bu(v);
                else       ((float*)Cv)[bz * sC + m * ldc + n] = v;
                if (do_vt) {
                    const int vc = n - vt_col0;
                    VTp[(long)(vc >> 6) * 65536 + (long)(vc & 63) * 1024 + m] = f2bu(v);
                }
            }
        }
    }
}

// ------- bf16 x bf16 GEMM (gram): tile 64x64, 5-buf gload_lds pipeline -------
__global__ __launch_bounds__(256)
void gemmG_k(const unsigned short* __restrict__ A, int lda,
             const unsigned short* __restrict__ B, int ldb,
             float* __restrict__ C, int ldc, int K)
{
    __shared__ __align__(16) short As[5][64 * 64];
    __shared__ __align__(16) short Bs[5][64 * 64];
    const int m0 = blockIdx.y * 64;
    const int n0 = blockIdx.x * 64;
    const int tid = threadIdx.x;
    const int w  = tid >> 6;
    const int l  = tid & 63;
    const int fr = l & 15;
    const int kc = l >> 4;

    f32x4 acc[4] = {};
    const int T = K >> 6;

    auto FILL = [&](int t, int buf) {
        const int k0 = t * 64;
        #pragma unroll
        for (int it = 0; it < 2; ++it) {
            const int row = w * 16 + it * 8 + (l >> 3);
            const int sl  = ((l & 7) ^ (row & 7)) * 8;
            gload16(A + (long)(m0 + row) * lda + k0 + sl, &As[buf][(w * 16 + it * 8) * 64]);
            gload16(B + (long)(n0 + row) * ldb + k0 + sl, &Bs[buf][(w * 16 + it * 8) * 64]);
        }
    };

    FILL(0, 0);
    if (T > 1) FILL(1, 1);
    if (T > 2) FILL(2, 2);
    if (T > 3) FILL(3, 3);
    int cb = 0, fb = 4;
    for (int t = 0; t < T; ++t) {
        const int rem = T - 1 - t;
        waitvm(rem >= 3 ? 12 : rem * 4);
        __builtin_amdgcn_sched_barrier(0);
        __builtin_amdgcn_s_barrier();
        if (t + 4 < T) FILL(t + 4, fb);
        fb = (fb == 4) ? 0 : fb + 1;
        #pragma unroll
        for (int ks = 0; ks < 2; ++ks) {
            const int arow = w * 16 + fr;
            const short8 af = *(const short8*)&As[cb][arow * 64 + (((ks * 4 + kc) ^ (arow & 7)) * 8)];
            #pragma unroll
            for (int c = 0; c < 4; ++c) {
                const int brow = c * 16 + fr;
                const short8 bf = *(const short8*)&Bs[cb][brow * 64 + (((ks * 4 + kc) ^ (brow & 7)) * 8)];
                acc[c] = __builtin_amdgcn_mfma_f32_16x16x32_bf16(af, bf, acc[c], 0, 0, 0);
            }
        }
        cb = (cb == 4) ? 0 : cb + 1;
    }

    #pragma unroll
    for (int c = 0; c < 4; ++c) {
        const int n = n0 + c * 16 + fr;
        #pragma unroll
        for (int i = 0; i < 4; ++i) {
            const long m = m0 + w * 16 + kc * 4 + i;
            C[m * ldc + n] = acc[c][i];
        }
    }
}

// ---------------- fused attention: O = softmax(QK^T/8) V ---------------------
// Grid (32 q-tiles of 32 rows, 8 heads), 128 thr = 2 waves.
__global__ __launch_bounds__(128)
void attn_k(const unsigned short* __restrict__ QKVb,   // [1024][1536]
            const unsigned short* __restrict__ VT,     // [8][64][1024]
            unsigned short* __restrict__ AOb)          // [1024][512]
{
    __shared__ __align__(16) short Ks[3][64 * 64];
    __shared__ __align__(16) short Vs[3][64 * 64];
    __shared__ __align__(16) short Ps[2][16 * 64];
    const int qt = blockIdx.x;
    const int h  = blockIdx.y;
    const int tid = threadIdx.x;
    const int w  = tid >> 6;
    const int l  = tid & 63;
    const int fr = l & 15;
    const int kc = l >> 4;

    const int qrow = qt * 32 + w * 16 + fr;
    short8 qf[2];
    qf[0] = *(const short8*)(QKVb + (long)qrow * 1536 + h * 64 + kc * 8);
    qf[1] = *(const short8*)(QKVb + (long)qrow * 1536 + h * 64 + 32 + kc * 8);

    auto FILL = [&](int t, int buf) {
        const int kb = t * 64;
        #pragma unroll
        for (int it = 0; it < 4; ++it) {
            const int row = it * 16 + w * 8 + (l >> 3);
            const int sl  = ((l & 7) ^ (row & 7)) * 8;
            gload16(QKVb + (long)(kb + row) * 1536 + 512 + h * 64 + sl,
                    &Ks[buf][(it * 16 + w * 8) * 64]);
            gload16(VT + (long)h * 65536 + (long)row * 1024 + kb + sl,
                    &Vs[buf][(it * 16 + w * 8) * 64]);
        }
    };

    float m_i[4], l_i[4];
    f32x4 acc_o[4] = {};
    #pragma unroll
    for (int i = 0; i < 4; ++i) { m_i[i] = -1e30f; l_i[i] = 0.f; }

    short* ps = &Ps[w][0];

    FILL(0, 0); FILL(1, 1);
    int fb = 2, cb = 0;
    for (int t = 0; t < 16; ++t) {
        waitvm(t == 15 ? 0 : 8);
        __builtin_amdgcn_sched_barrier(0);
        __builtin_amdgcn_s_barrier();
        if (t + 2 < 16) { FILL(t + 2, fb); fb = (fb == 2) ? 0 : fb + 1; }

        f32x4 sacc[4] = {};
        #pragma unroll
        for (int ks = 0; ks < 2; ++ks) {
            #pragma unroll
            for (int c = 0; c < 4; ++c) {
                const int krow = c * 16 + fr;
                const short8 kf = *(const short8*)&Ks[cb][krow * 64 + (((ks * 4 + kc) ^ (krow & 7)) * 8)];
                sacc[c] = __builtin_amdgcn_mfma_f32_16x16x32_bf16(qf[ks], kf, sacc[c], 0, 0, 0);
            }
        }

        float p[4][4];
        #pragma unroll
        for (int i = 0; i < 4; ++i) {
            float tm = fmaxf(fmaxf(sacc[0][i], sacc[1][i]), fmaxf(sacc[2][i], sacc[3][i]));
            #pragma unroll
            for (int off = 8; off; off >>= 1) tm = fmaxf(tm, __shfl_xor(tm, off));
            tm *= 0.125f;
            const float mn = fmaxf(m_i[i], tm);
            const float sc = __expf(m_i[i] - mn);
            m_i[i] = mn;
            float ts = 0.f;
            #pragma unroll
            for (int c = 0; c < 4; ++c) { p[c][i] = __expf(sacc[c][i] * 0.125f - mn); ts += p[c][i]; }
            #pragma unroll
            for (int off = 8; off; off >>= 1) ts += __shfl_xor(ts, off);
            l_i[i] = l_i[i] * sc + ts;
            #pragma unroll
            for (int c = 0; c < 4; ++c) acc_o[c][i] *= sc;
        }

        #pragma unroll
        for (int c = 0; c < 4; ++c) {
            const int col = c * 16 + fr;
            #pragma unroll
            for (int i = 0; i < 4; ++i) {
                const int row = kc * 4 + i;
                ps[row * 64 + (((col >> 3) ^ (row & 7)) * 8) + (col & 7)] = (short)f2bu(p[c][i]);
            }
        }
        short8 pf[2];
        pf[0] = *(const short8*)&ps[fr * 64 + ((kc ^ (fr & 7)) * 8)];
        pf[1] = *(const short8*)&ps[fr * 64 + (((4 + kc) ^ (fr & 7)) * 8)];

        #pragma unroll
        for (int ks = 0; ks < 2; ++ks) {
            #pragma unroll
            for (int c = 0; c < 4; ++c) {
                const int drow = c * 16 + fr;
                const short8 vf = *(const short8*)&Vs[cb][drow * 64 + (((ks * 4 + kc) ^ (drow & 7)) * 8)];
                acc_o[c] = __builtin_amdgcn_mfma_f32_16x16x32_bf16(pf[ks], vf, acc_o[c], 0, 0, 0);
            }
        }
        cb = (cb == 2) ? 0 : cb + 1;
    }

    #pragma unroll
    for (int c = 0; c < 4; ++c) {
        const int dcol = h * 64 + c * 16 + fr;
        #pragma unroll
        for (int i = 0; i < 4; ++i) {
            const int row = qt * 32 + w * 16 + kc * 4 + i;
            AOb[(long)row * 512 + dcol] = f2bu(acc_o[c][i] / l_i[i]);
        }
    }
}

// -------- LayerNorm-as-merge: out = LN(x + sum_slabs + bias)*s + b -----------
template<int NSLAB>
__global__ __launch_bounds__(256)
void ln_k(const float* __restrict__ x, const float* __restrict__ slab,
          const float* __restrict__ bias,
          const float* __restrict__ s, const float* __restrict__ b,
          float* __restrict__ out, unsigned short* __restrict__ outb)
{
    const int lane = threadIdx.x & 63;
    const int row  = (blockIdx.x << 2) + (threadIdx.x >> 6);
    const float* px = x + (long)row * 512;
    float v[8];
    float sum = 0.f;
    #pragma unroll
    for (int i = 0; i < 8; ++i) {
        const int j = lane + (i << 6);
        v[i] = px[j];
        #pragma unroll
        for (int t = 0; t < NSLAB; ++t) v[i] += slab[(long)t * 524288 + (long)row * 512 + j];
        if (NSLAB > 0) v[i] += bias[j];
        sum += v[i];
    }
    #pragma unroll
    for (int off = 32; off; off >>= 1) sum += __shfl_xor(sum, off);
    const float m = sum * (1.0f / 512.0f);
    float s2 = 0.f;
    #pragma unroll
    for (int i = 0; i < 8; ++i) { const float d = v[i] - m; s2 += d * d; }
    #pragma unroll
    for (int off = 32; off; off >>= 1) s2 += __shfl_xor(s2, off);
    const float inv = rsqrtf(s2 * (1.0f / 512.0f) + 1e-5f);
    #pragma unroll
    for (int i = 0; i < 8; ++i) {
        const int j = lane + (i << 6);
        const float r = (v[i] - m) * inv * s[j] + b[j];
        out[(long)row * 512 + j] = r;
        if (outb) outb[(long)row * 512 + j] = f2bu(r);
    }
}

// -------- fused final LN + L2-normalize --------------------------------------
__global__ __launch_bounds__(256)
void lnl2_k(const float* __restrict__ x,
            const float* __restrict__ s, const float* __restrict__ b,
            float* __restrict__ out_attn, unsigned short* __restrict__ nb)
{
    const int lane = threadIdx.x & 63;
    const int row  = (blockIdx.x << 2) + (threadIdx.x >> 6);
    const float* px = x + (long)row * 512;
    float v[8];
    float sum = 0.f;
    #pragma unroll
    for (int i = 0; i < 8; ++i) { v[i] = px[lane + (i << 6)]; sum += v[i]; }
    #pragma unroll
    for (int off = 32; off; off >>= 1) sum += __shfl_xor(sum, off);
    const float m = sum * (1.0f / 512.0f);
    float s2 = 0.f;
    #pragma unroll
    for (int i = 0; i < 8; ++i) { const float d = v[i] - m; s2 += d * d; }
    #pragma unroll
    for (int off = 32; off; off >>= 1) s2 += __shfl_xor(s2, off);
    const float inv = rsqrtf(s2 * (1.0f / 512.0f) + 1e-5f);
    float nrm = 0.f;
    #pragma unroll
    for (int i = 0; i < 8; ++i) {
        const int j = lane + (i << 6);
        v[i] = (v[i] - m) * inv * s[j] + b[j];
        out_attn[(long)row * 512 + j] = v[i];
        nrm += v[i] * v[i];
    }
    #pragma unroll
    for (int off = 32; off; off >>= 1) nrm += __shfl_xor(nrm, off);
    const float rinv = rsqrtf(nrm);
    #pragma unroll
    for (int i = 0; i < 8; ++i)
        nb[(long)row * 512 + lane + (i << 6)] = f2bu(v[i] * rinv);
}

// -------- init: x -> MEMf, Yf (fp32) + MEMb, Yb (bf16) -----------------------
__global__ __launch_bounds__(256)
void init_k(const float* __restrict__ x, float* __restrict__ mf, float* __restrict__ yf,
            unsigned short* __restrict__ mb, unsigned short* __restrict__ yb)
{
    const long i = ((long)blockIdx.x * 256 + threadIdx.x) * 4;
    const float4 v = *(const float4*)(x + i);
    *(float4*)(mf + i) = v;
    *(float4*)(yf + i) = v;
    short4v s;
    s[0] = (short)f2bu(v.x); s[1] = (short)f2bu(v.y);
    s[2] = (short)f2bu(v.z); s[3] = (short)f2bu(v.w);
    *(short4v*)(mb + i) = s;
    *(short4v*)(yb + i) = s;
}

// ------------------------------ host side ------------------------------------
static void gemmW(hipStream_t st, bool relu, bool obf16,
                  const unsigned short* A, const unsigned short* A2, int a2_col,
                  int lda, const float* B, int ldb,
                  const float* bias, void* C, int ldc, long sC,
                  int M, int N, int K, int batch,
                  unsigned short* VTp = nullptr, int vt_col0 = 0, int kz = 0)
{
    dim3 g(N / 64, M / 128, batch);
    if (obf16) {
        if (relu) gemmW_k<true,  true ><<<g, 256, 0, st>>>(A, A2, a2_col, lda, B, ldb, bias, C, ldc, sC, K, VTp, vt_col0, kz);
        else      gemmW_k<false, true ><<<g, 256, 0, st>>>(A, A2, a2_col, lda, B, ldb, bias, C, ldc, sC, K, VTp, vt_col0, kz);
    } else {
        if (relu) gemmW_k<true,  false><<<g, 256, 0, st>>>(A, A2, a2_col, lda, B, ldb, bias, C, ldc, sC, K, VTp, vt_col0, kz);
        else      gemmW_k<false, false><<<g, 256, 0, st>>>(A, A2, a2_col, lda, B, ldb, bias, C, ldc, sC, K, VTp, vt_col0, kz);
    }
}

extern "C" void kernel_launch(void* const* d_in, const int* in_sizes, int n_in,
                              void* d_out, int out_size, void* d_ws, size_t ws_size,
                              hipStream_t stream)
{
    const float* x            = (const float*)d_in[0];
    const float* enc_qkv_w    = (const float*)d_in[1];
    const float* enc_qkv_b    = (const float*)d_in[2];
    const float* enc_out_w    = (const float*)d_in[3];
    const float* enc_out_b    = (const float*)d_in[4];
    const float* enc_ff1_w    = (const float*)d_in[5];
    const float* enc_ff1_b    = (const float*)d_in[6];
    const float* enc_ff2_w    = (const float*)d_in[7];
    const float* enc_ff2_b    = (const float*)d_in[8];
    const float* enc_ln1_s    = (const float*)d_in[9];
    const float* enc_ln1_b    = (const float*)d_in[10];
    const float* enc_ln2_s    = (const float*)d_in[11];
    const float* enc_ln2_b    = (const float*)d_in[12];
    const float* dec_sa_qkv_w = (const float*)d_in[13];
    const float* dec_sa_qkv_b = (const float*)d_in[14];
    const float* dec_sa_out_w = (const float*)d_in[15];
    const float* dec_sa_out_b = (const float*)d_in[16];
    const float* dec_ca_qkv_w = (const float*)d_in[17];
    const float* dec_ca_qkv_b = (const float*)d_in[18];
    const float* dec_ca_out_w = (const float*)d_in[19];
    const float* dec_ca_out_b = (const float*)d_in[20];
    const float* dec_ff1_w    = (const float*)d_in[21];
    const float* dec_ff1_b    = (const float*)d_in[22];
    const float* dec_ff2_w    = (const float*)d_in[23];
    const float* dec_ff2_b    = (const float*)d_in[24];
    const float* dec_ln1_s    = (const float*)d_in[25];
    const float* dec_ln1_b    = (const float*)d_in[26];
    const float* dec_ln2_s    = (const float*)d_in[27];
    const float* dec_ln2_b    = (const float*)d_in[28];
    const float* dec_ln3_s    = (const float*)d_in[29];
    const float* dec_ln3_b    = (const float*)d_in[30];
    const float* enc_norm_s   = (const float*)d_in[31];
    const float* enc_norm_b   = (const float*)d_in[32];
    const float* dec_norm_s   = (const float*)d_in[33];
    const float* dec_norm_b   = (const float*)d_in[34];

    char* p = (char*)d_ws;
    auto alloc = [&](size_t bytes) -> char* {
        char* r = p; p += (bytes + 255) & ~(size_t)255; return r;
    };
    float*          MEMf = (float*)alloc(1024 * 512 * 4);
    float*          Yf   = (float*)alloc(1024 * 512 * 4);
    unsigned short* MEMb = (unsigned short*)alloc(1024 * 512 * 2);
    unsigned short* Yb   = (unsigned short*)alloc(1024 * 512 * 2);
    unsigned short* QKVb = (unsigned short*)alloc(1024 * 1536 * 2);
    unsigned short* VT   = (unsigned short*)alloc(8L * 64 * 1024 * 2);
    unsigned short* AOb  = (unsigned short*)alloc(1024 * 512 * 2);
    float*          SLAB = (float*)alloc(4L * 1024 * 512 * 4);
    unsigned short* F1b  = (unsigned short*)alloc(1024L * 2048 * 2);
    unsigned short* NBb  = (unsigned short*)alloc(1024 * 512 * 2);

    float* out_gram = (float*)d_out;
    float* out_attn = out_gram + 1024 * 1024;

    // attention: merged QKV GEMM (fp32 W) -> fused attn -> proj split-K(2) slabs
    auto run_attn = [&](const unsigned short* qb, const unsigned short* kvb,
                        const float* wqkv, const float* bqkv, const float* wo) {
        gemmW(stream, false, true, qb, (qb == kvb) ? nullptr : kvb, 512, 512,
              wqkv, 512, bqkv, QKVb, 1536, 0, 1024, 1536, 512, 1, VT, 1024, 0);
        attn_k<<<dim3(32, 8), 128, 0, stream>>>(QKVb, VT, AOb);
        gemmW(stream, false, false, AOb, nullptr, 0, 512, wo, 512, nullptr,
              SLAB, 512, 524288, 1024, 512, 256, 2, nullptr, 0, 256);
    };
    // FFN: FF1 (relu, bf16 out) -> FF2 split-K(4) slabs
    auto run_ffn = [&](const unsigned short* inb, const float* w1, const float* b1,
                       const float* w2) {
        gemmW(stream, true, true, inb, nullptr, 0, 512, w1, 512, b1,
              F1b, 2048, 0, 1024, 2048, 512, 1);
        gemmW(stream, false, false, F1b, nullptr, 0, 2048, w2, 2048, nullptr,
              SLAB, 512, 524288, 1024, 512, 512, 4, nullptr, 0, 512);
    };

    init_k<<<512, 256, 0, stream>>>(x, MEMf, Yf, MEMb, Yb);

    // ----------------------------- encoder -----------------------------------
    for (int i = 0; i < NLAY; ++i) {
        run_attn(MEMb, MEMb, enc_qkv_w + (long)i * 1536 * 512, enc_qkv_b + i * 1536,
                 enc_out_w + (long)i * 512 * 512);
        ln_k<2><<<256, 256, 0, stream>>>(MEMf, SLAB, enc_out_b + i * 512,
                                         enc_ln1_s + i * 512, enc_ln1_b + i * 512, MEMf, MEMb);
        run_ffn(MEMb, enc_ff1_w + (long)i * 2048 * 512, enc_ff1_b + i * 2048,
                enc_ff2_w + (long)i * 512 * 2048);
        ln_k<4><<<256, 256, 0, stream>>>(MEMf, SLAB, enc_ff2_b + i * 512,
                                         enc_ln2_s + i * 512, enc_ln2_b + i * 512, MEMf, MEMb);
    }
    ln_k<0><<<256, 256, 0, stream>>>(MEMf, nullptr, nullptr, enc_norm_s, enc_norm_b, MEMf, MEMb);

    // ----------------------------- decoder -----------------------------------
    for (int i = 0; i < NLAY; ++i) {
        run_attn(Yb, Yb, dec_sa_qkv_w + (long)i * 1536 * 512, dec_sa_qkv_b + i * 1536,
                 dec_sa_out_w + (long)i * 512 * 512);
        ln_k<2><<<256, 256, 0, stream>>>(Yf, SLAB, dec_sa_out_b + i * 512,
                                         dec_ln1_s + i * 512, dec_ln1_b + i * 512, Yf, Yb);

        run_attn(Yb, MEMb, dec_ca_qkv_w + (long)i * 1536 * 512, dec_ca_qkv_b + i * 1536,
                 dec_ca_out_w + (long)i * 512 * 512);
        ln_k<2><<<256, 256, 0, stream>>>(Yf, SLAB, dec_ca_out_b + i * 512,
                                         dec_ln2_s + i * 512, dec_ln2_b + i * 512, Yf, Yb);

        run_ffn(Yb, dec_ff1_w + (long)i * 2048 * 512, dec_ff1_b + i * 2048,
                dec_ff2_w + (long)i * 512 * 2048);
        ln_k<4><<<256, 256, 0, stream>>>(Yf, SLAB, dec_ff2_b + i * 512,
                                         dec_ln3_s + i * 512, dec_ln3_b + i * 512, Yf, Yb);
    }

    // final: attention_out + n = rownorm (fused), gram = n@n^T
    lnl2_k<<<256, 256, 0, stream>>>(Yf, dec_norm_s, dec_norm_b, out_attn, NBb);
    gemmG_k<<<dim3(16, 16), 256, 0, stream>>>(NBb, 512, NBb, 512, out_gram, 1024, 512);
}